// Round 1
// baseline (1050.942 us; speedup 1.0000x reference)
//
#include <hip/hip_runtime.h>
#include <hip/hip_bf16.h>
#include <math.h>

// Problem constants
#define TSEQ   2048
#define HID    4096
#define NH     32
#define NKV    8
#define HD     128
#define QKVN   6144              // NH*HD + 2*NKV*HD
#define GSCALE 0.08838834764831845f   // HD^-0.5
#define LOG_THETA 13.122363377404328f // ln(500000)

typedef __bf16 bf16_t;
typedef __attribute__((ext_vector_type(8))) __bf16 bf16x8;
typedef __attribute__((ext_vector_type(4))) float f32x4;

// ---------------- f32 -> bf16 elementwise convert ----------------
__global__ __launch_bounds__(256) void k_f32_to_bf16(const float* __restrict__ in,
                                                     bf16_t* __restrict__ out, int n) {
  int i = (blockIdx.x * 256 + threadIdx.x) * 4;
  if (i >= n) return;
  float4 v = *(const float4*)(in + i);
  bf16_t o0 = (bf16_t)v.x, o1 = (bf16_t)v.y, o2 = (bf16_t)v.z, o3 = (bf16_t)v.w;
  typedef __attribute__((ext_vector_type(4))) __bf16 bf16x4;
  bf16x4 o = {o0, o1, o2, o3};
  *(bf16x4*)(out + i) = o;
}

// ---------------- f32 [R][C] -> bf16 [C][R] transpose-convert ----------------
__global__ __launch_bounds__(256) void k_transpose_f32_bf16(const float* __restrict__ in,
                                                            bf16_t* __restrict__ out,
                                                            int R, int C) {
  __shared__ float tile[32][33];
  int tx = threadIdx.x & 31, ty = threadIdx.x >> 5;
  int c0 = blockIdx.x * 32, r0 = blockIdx.y * 32;
#pragma unroll
  for (int i = 0; i < 4; i++)
    tile[ty + i * 8][tx] = in[(size_t)(r0 + ty + i * 8) * C + c0 + tx];
  __syncthreads();
#pragma unroll
  for (int i = 0; i < 4; i++)
    out[(size_t)(c0 + ty + i * 8) * R + r0 + tx] = (bf16_t)tile[tx][ty + i * 8];
}

// ---------------- RoPE (interleaved) in-place on qkv; folds GSCALE into q ----------------
__global__ __launch_bounds__(256) void k_rope(bf16_t* __restrict__ qkv,
                                              const int* __restrict__ positions) {
  int idx = blockIdx.x * 256 + threadIdx.x;   // 0..2559 = 40 heads * 64 pairs
  int t = blockIdx.y;
  int i = idx & 63;          // pair index 0..63
  int hh = idx >> 6;         // 0..39 (0..31 = q heads, 32..39 = k heads)
  if (hh >= 40) return;
  int col = (hh < 32) ? (hh * 128 + 2 * i) : (4096 + (hh - 32) * 128 + 2 * i);
  size_t base = (size_t)t * QKVN + col;
  float x1 = (float)qkv[base];
  float x2 = (float)qkv[base + 1];
  float p = (float)positions[t];
  float inv = expf(-(float)i * (LOG_THETA / 64.0f));
  float ang = p * inv;
  float s, c;
  sincosf(ang, &s, &c);
  float o1 = x1 * c - x2 * s;
  float o2 = x2 * c + x1 * s;
  float sc = (hh < 32) ? GSCALE : 1.0f;
  qkv[base]     = (bf16_t)(o1 * sc);
  qkv[base + 1] = (bf16_t)(o2 * sc);
}

// ---------------- transpose V: qkv[:, 5120+c] (T x 1024) -> vT [1024][T] ----------------
__global__ __launch_bounds__(256) void k_transpose_v(const bf16_t* __restrict__ qkv,
                                                     bf16_t* __restrict__ vT) {
  __shared__ bf16_t tile[32][33];
  int tx = threadIdx.x & 31, ty = threadIdx.x >> 5;
  int t0 = blockIdx.x * 32;   // seq tile
  int c0 = blockIdx.y * 32;   // channel tile (kv*128+d)
#pragma unroll
  for (int i = 0; i < 4; i++)
    tile[ty + i * 8][tx] = qkv[(size_t)(t0 + ty + i * 8) * QKVN + 5120 + c0 + tx];
  __syncthreads();
#pragma unroll
  for (int i = 0; i < 4; i++)
    vT[(size_t)(c0 + ty + i * 8) * TSEQ + t0 + tx] = tile[tx][ty + i * 8];
}

// ---------------- GEMM: C[M][N] = A[M][K] * Bt[N][K]^T  (bf16 in, f32 acc) ----------------
// BM=BN=128, BK=64, 256 threads (4 waves, 2x2), each wave 64x64 via 4x4 16x16x32 MFMA frags.
template <int OUT_F32>
__global__ __launch_bounds__(256) void k_gemm_bt(const bf16_t* __restrict__ A,
                                                 const bf16_t* __restrict__ Bt,
                                                 void* __restrict__ Cout,
                                                 int M, int N, int K) {
  __shared__ bf16_t As[128][88];   // pad to stride 88 (176B, 16B-aligned, ~2-way banks)
  __shared__ bf16_t Bs[128][88];
  const int tid = threadIdx.x;
  const int lane = tid & 63, wave = tid >> 6;
  const int l15 = lane & 15, lhi = lane >> 4;
  const int bm = blockIdx.y * 128, bn = blockIdx.x * 128;
  const int wr = (wave >> 1) * 64, wc = (wave & 1) * 64;

  f32x4 acc[4][4] = {};

  const int srow = tid >> 3;        // 0..31 (+32*r)
  const int skc = (tid & 7) * 8;    // k-chunk within BK=64
  const bf16_t* Ap = A + (size_t)(bm + srow) * K + skc;
  const bf16_t* Bp = Bt + (size_t)(bn + srow) * K + skc;

  for (int bk = 0; bk < K; bk += 64) {
    float4 ra[4], rb[4];
#pragma unroll
    for (int r = 0; r < 4; r++) {
      ra[r] = *(const float4*)(Ap + (size_t)(r * 32) * K + bk);
      rb[r] = *(const float4*)(Bp + (size_t)(r * 32) * K + bk);
    }
    __syncthreads();
#pragma unroll
    for (int r = 0; r < 4; r++) {
      *(float4*)&As[srow + r * 32][skc] = ra[r];
      *(float4*)&Bs[srow + r * 32][skc] = rb[r];
    }
    __syncthreads();
#pragma unroll
    for (int ks = 0; ks < 2; ks++) {
      bf16x8 af[4], bfr[4];
#pragma unroll
      for (int i = 0; i < 4; i++)
        af[i] = *(const bf16x8*)&As[wr + i * 16 + l15][ks * 32 + lhi * 8];
#pragma unroll
      for (int j = 0; j < 4; j++)
        bfr[j] = *(const bf16x8*)&Bs[wc + j * 16 + l15][ks * 32 + lhi * 8];
#pragma unroll
      for (int i = 0; i < 4; i++)
#pragma unroll
        for (int j = 0; j < 4; j++)
          acc[i][j] = __builtin_amdgcn_mfma_f32_16x16x32_bf16(af[i], bfr[j], acc[i][j], 0, 0, 0);
    }
  }

#pragma unroll
  for (int i = 0; i < 4; i++)
#pragma unroll
    for (int j = 0; j < 4; j++)
#pragma unroll
      for (int b = 0; b < 4; b++) {
        int row = bm + wr + i * 16 + lhi * 4 + b;
        int col = bn + wc + j * 16 + l15;
        float v = acc[i][j][b];
        if (OUT_F32)
          ((float*)Cout)[(size_t)row * N + col] = v;
        else
          ((bf16_t*)Cout)[(size_t)row * N + col] = (bf16_t)v;
      }
}

// ---------------- Flash attention (causal, GQA) ----------------
// grid (NH, T/128); 256 threads = 4 waves, wave w owns q-rows [w*32, w*32+32).
// KV tile = 64. Q pre-scaled by GSCALE in rope.
__global__ __launch_bounds__(256) void k_flash(const bf16_t* __restrict__ qkv,
                                               const bf16_t* __restrict__ vT,
                                               bf16_t* __restrict__ attn) {
  __shared__ bf16_t Kl[64][152];   // [s][d] pad 152 (304B stride)
  __shared__ bf16_t Vl[128][88];   // [d][s] pad 88
  __shared__ bf16_t Pl[128][88];   // [t][s] pad 88
  const int h = blockIdx.x;
  const int qt = blockIdx.y;
  const int kvh = h >> 2;
  const int tid = threadIdx.x, lane = tid & 63, wave = tid >> 6;
  const int l15 = lane & 15, lhi = lane >> 4;
  const int qbase = qt * 128, wrow = wave * 32;

  // Q fragments, persistent in registers
  bf16x8 qf[2][4];
#pragma unroll
  for (int i = 0; i < 2; i++)
#pragma unroll
    for (int ks = 0; ks < 4; ks++)
      qf[i][ks] = *(const bf16x8*)&qkv[(size_t)(qbase + wrow + i * 16 + l15) * QKVN +
                                       h * 128 + ks * 32 + lhi * 8];

  f32x4 o[2][8] = {};
  float m_i[2][4], l_i[2][4];
#pragma unroll
  for (int i = 0; i < 2; i++)
#pragma unroll
    for (int b = 0; b < 4; b++) { m_i[i][b] = -1e30f; l_i[i][b] = 0.f; }

  const int ktmax = (qbase + 127) >> 6;
  for (int kt = 0; kt <= ktmax; kt++) {
    // stage K (64x128) and Vt (128x64) via regs
    float4 rk[4], rv[4];
#pragma unroll
    for (int r = 0; r < 4; r++) {
      int ck = r * 256 + tid;
      int s = ck >> 4, dc = (ck & 15) * 8;
      rk[r] = *(const float4*)&qkv[(size_t)(kt * 64 + s) * QKVN + 4096 + kvh * 128 + dc];
      int d = ck >> 3, scc = (ck & 7) * 8;
      rv[r] = *(const float4*)&vT[(size_t)(kvh * 128 + d) * TSEQ + kt * 64 + scc];
    }
    __syncthreads();
#pragma unroll
    for (int r = 0; r < 4; r++) {
      int ck = r * 256 + tid;
      int s = ck >> 4, dc = (ck & 15) * 8;
      *(float4*)&Kl[s][dc] = rk[r];
      int d = ck >> 3, scc = (ck & 7) * 8;
      *(float4*)&Vl[d][scc] = rv[r];
    }
    __syncthreads();

    // S = Q * K^T  (per wave: 32 x 64)
    f32x4 sa[2][4] = {};
#pragma unroll
    for (int ks = 0; ks < 4; ks++) {
      bf16x8 kb[4];
#pragma unroll
      for (int j = 0; j < 4; j++)
        kb[j] = *(const bf16x8*)&Kl[j * 16 + l15][ks * 32 + lhi * 8];
#pragma unroll
      for (int i = 0; i < 2; i++)
#pragma unroll
        for (int j = 0; j < 4; j++)
          sa[i][j] = __builtin_amdgcn_mfma_f32_16x16x32_bf16(qf[i][ks], kb[j], sa[i][j], 0, 0, 0);
    }

    // mask + online softmax
#pragma unroll
    for (int i = 0; i < 2; i++) {
#pragma unroll
      for (int b = 0; b < 4; b++) {
        int trow = qbase + wrow + i * 16 + lhi * 4 + b;
        float mx = -1e30f;
#pragma unroll
        for (int j = 0; j < 4; j++) {
          int scol = kt * 64 + j * 16 + l15;
          if (scol > trow) sa[i][j][b] = -1e30f;
          mx = fmaxf(mx, sa[i][j][b]);
        }
#pragma unroll
        for (int off = 1; off < 16; off <<= 1) mx = fmaxf(mx, __shfl_xor(mx, off));
        float mn = fmaxf(m_i[i][b], mx);
        float corr = __expf(m_i[i][b] - mn);
        float sum = 0.f;
#pragma unroll
        for (int j = 0; j < 4; j++) {
          float pv = __expf(sa[i][j][b] - mn);
          sa[i][j][b] = pv;
          sum += pv;
        }
#pragma unroll
        for (int off = 1; off < 16; off <<= 1) sum += __shfl_xor(sum, off);
        l_i[i][b] = l_i[i][b] * corr + sum;
        m_i[i][b] = mn;
#pragma unroll
        for (int j = 0; j < 8; j++) o[i][j][b] *= corr;
#pragma unroll
        for (int j = 0; j < 4; j++)
          Pl[wrow + i * 16 + lhi * 4 + b][j * 16 + l15] = (bf16_t)sa[i][j][b];
      }
    }

    // O += P * V   (P: 32x64 A-frags via LDS; V: B-frags from Vl)
#pragma unroll
    for (int ks = 0; ks < 2; ks++) {
      bf16x8 pa[2], vb[8];
#pragma unroll
      for (int i = 0; i < 2; i++)
        pa[i] = *(const bf16x8*)&Pl[wrow + i * 16 + l15][ks * 32 + lhi * 8];
#pragma unroll
      for (int j = 0; j < 8; j++)
        vb[j] = *(const bf16x8*)&Vl[j * 16 + l15][ks * 32 + lhi * 8];
#pragma unroll
      for (int i = 0; i < 2; i++)
#pragma unroll
        for (int j = 0; j < 8; j++)
          o[i][j] = __builtin_amdgcn_mfma_f32_16x16x32_bf16(pa[i], vb[j], o[i][j], 0, 0, 0);
    }
    __syncthreads();
  }

  // write attn output (bf16), divided by l
#pragma unroll
  for (int i = 0; i < 2; i++)
#pragma unroll
    for (int j = 0; j < 8; j++)
#pragma unroll
      for (int b = 0; b < 4; b++) {
        int trow = qbase + wrow + i * 16 + lhi * 4 + b;
        attn[(size_t)trow * (NH * HD) + h * 128 + j * 16 + l15] =
            (bf16_t)(o[i][j][b] / l_i[i][b]);
      }
}

// ---------------- launcher ----------------
extern "C" void kernel_launch(void* const* d_in, const int* in_sizes, int n_in,
                              void* d_out, int out_size, void* d_ws, size_t ws_size,
                              hipStream_t stream) {
  const int* positions = (const int*)d_in[0];
  const float* hs = (const float*)d_in[1];
  const float* wqkv = (const float*)d_in[2];
  const float* wo = (const float*)d_in[3];
  float* out = (float*)d_out;

  char* ws = (char*)d_ws;
  bf16_t* hsb   = (bf16_t*)(ws);                       // 16.78 MB  (reused as attn later)
  bf16_t* wqkvT = (bf16_t*)(ws + 16777216);            // 50.33 MB
  bf16_t* woT   = (bf16_t*)(ws + 67108864);            // 33.55 MB
  bf16_t* qkv   = (bf16_t*)(ws + 100663296);           // 25.17 MB
  bf16_t* vT    = (bf16_t*)(ws + 125829120);           //  4.19 MB
  bf16_t* attn  = hsb;                                 // reuse (hsb dead after GEMM1)

  // 1. convert hidden_states
  k_f32_to_bf16<<<(TSEQ * HID / 4 + 255) / 256, 256, 0, stream>>>(hs, hsb, TSEQ * HID);
  // 2. transpose-convert weights to [N][K]
  k_transpose_f32_bf16<<<dim3(QKVN / 32, HID / 32), 256, 0, stream>>>(wqkv, wqkvT, HID, QKVN);
  k_transpose_f32_bf16<<<dim3(HID / 32, HID / 32), 256, 0, stream>>>(wo, woT, NH * HD, HID);
  // 3. QKV projection -> qkv bf16 [T][6144]
  k_gemm_bt<0><<<dim3(QKVN / 128, TSEQ / 128), 256, 0, stream>>>(hsb, wqkvT, qkv, TSEQ, QKVN, HID);
  // 4. RoPE in place (q scaled)
  k_rope<<<dim3(10, TSEQ), 256, 0, stream>>>(qkv, positions);
  // 5. transpose V -> vT [1024][T]
  k_transpose_v<<<dim3(TSEQ / 32, 1024 / 32), 256, 0, stream>>>(qkv, vT);
  // 6. flash attention -> attn bf16 [T][4096]
  k_flash<<<dim3(NH, TSEQ / 128), 256, 0, stream>>>(qkv, vT, attn);
  // 7. output projection -> f32 out
  k_gemm_bt<1><<<dim3(HID / 128, TSEQ / 128), 256, 0, stream>>>(attn, woT, out, TSEQ, HID, HID);
}

// Round 2
// 550.166 us; speedup vs baseline: 1.9102x; 1.9102x over previous
//
#include <hip/hip_runtime.h>
#include <hip/hip_bf16.h>
#include <math.h>

// Problem constants
#define TSEQ   2048
#define HID    4096
#define NH     32
#define NKV    8
#define HD     128
#define QKVN   6144              // NH*HD + 2*NKV*HD
#define GSCALE 0.08838834764831845f   // HD^-0.5
#define LOG_THETA 13.122363377404328f // ln(500000)

typedef __bf16 bf16_t;
typedef __attribute__((ext_vector_type(8))) __bf16 bf16x8;
typedef __attribute__((ext_vector_type(4))) float f32x4;

// async global->LDS, 16B per lane; LDS dest is wave-uniform base + lane*16
#define GLOAD_LDS16(gp, lp)                                                    \
  __builtin_amdgcn_global_load_lds(                                            \
      (const __attribute__((address_space(1))) void*)(gp),                     \
      (__attribute__((address_space(3))) void*)(lp), 16, 0, 0)

// ---------------- f32 -> bf16 elementwise convert ----------------
__global__ __launch_bounds__(256) void k_f32_to_bf16(const float* __restrict__ in,
                                                     bf16_t* __restrict__ out, int n) {
  int i = (blockIdx.x * 256 + threadIdx.x) * 4;
  if (i >= n) return;
  float4 v = *(const float4*)(in + i);
  bf16_t o0 = (bf16_t)v.x, o1 = (bf16_t)v.y, o2 = (bf16_t)v.z, o3 = (bf16_t)v.w;
  typedef __attribute__((ext_vector_type(4))) __bf16 bf16x4;
  bf16x4 o = {o0, o1, o2, o3};
  *(bf16x4*)(out + i) = o;
}

// ---------------- f32 [R][C] -> bf16 [C][R] transpose-convert ----------------
__global__ __launch_bounds__(256) void k_transpose_f32_bf16(const float* __restrict__ in,
                                                            bf16_t* __restrict__ out,
                                                            int R, int C) {
  __shared__ float tile[32][33];
  int tx = threadIdx.x & 31, ty = threadIdx.x >> 5;
  int c0 = blockIdx.x * 32, r0 = blockIdx.y * 32;
#pragma unroll
  for (int i = 0; i < 4; i++)
    tile[ty + i * 8][tx] = in[(size_t)(r0 + ty + i * 8) * C + c0 + tx];
  __syncthreads();
#pragma unroll
  for (int i = 0; i < 4; i++)
    out[(size_t)(c0 + ty + i * 8) * R + r0 + tx] = (bf16_t)tile[tx][ty + i * 8];
}

// ---------------- RoPE (interleaved) in-place on qkv; folds GSCALE into q ----------------
__global__ __launch_bounds__(256) void k_rope(bf16_t* __restrict__ qkv,
                                              const int* __restrict__ positions) {
  int idx = blockIdx.x * 256 + threadIdx.x;   // 0..2559 = 40 heads * 64 pairs
  int t = blockIdx.y;
  int i = idx & 63;          // pair index 0..63
  int hh = idx >> 6;         // 0..39 (0..31 = q heads, 32..39 = k heads)
  if (hh >= 40) return;
  int col = (hh < 32) ? (hh * 128 + 2 * i) : (4096 + (hh - 32) * 128 + 2 * i);
  size_t base = (size_t)t * QKVN + col;
  float x1 = (float)qkv[base];
  float x2 = (float)qkv[base + 1];
  float p = (float)positions[t];
  float inv = expf(-(float)i * (LOG_THETA / 64.0f));
  float ang = p * inv;
  float s, c;
  sincosf(ang, &s, &c);
  float o1 = x1 * c - x2 * s;
  float o2 = x2 * c + x1 * s;
  float sc = (hh < 32) ? GSCALE : 1.0f;
  qkv[base]     = (bf16_t)(o1 * sc);
  qkv[base + 1] = (bf16_t)(o2 * sc);
}

// ---------------- transpose V: qkv[:, 5120+c] (T x 1024) -> vT [1024][T] ----------------
__global__ __launch_bounds__(256) void k_transpose_v(const bf16_t* __restrict__ qkv,
                                                     bf16_t* __restrict__ vT) {
  __shared__ bf16_t tile[32][33];
  int tx = threadIdx.x & 31, ty = threadIdx.x >> 5;
  int t0 = blockIdx.x * 32;   // seq tile
  int c0 = blockIdx.y * 32;   // channel tile (kv*128+d)
#pragma unroll
  for (int i = 0; i < 4; i++)
    tile[ty + i * 8][tx] = qkv[(size_t)(t0 + ty + i * 8) * QKVN + 5120 + c0 + tx];
  __syncthreads();
#pragma unroll
  for (int i = 0; i < 4; i++)
    vT[(size_t)(c0 + ty + i * 8) * TSEQ + t0 + tx] = tile[tx][ty + i * 8];
}

// ---------------- GEMM (m97 structure): C[M][N] = A[M][K] * Bt[N][K]^T ----------------
// BM=BN=128, BK=64, 256 threads (4 waves, 2x2), wave = 64x64 via 4x4 16x16x32 MFMA.
// Staging: global_load_lds dwordx4, linear LDS [128][64] per matrix (16 KB each).
// 2-barrier loop: stage -> barrier -> compute -> barrier.
template <int OUT_F32>
__global__ __launch_bounds__(256) void k_gemm_lds(const bf16_t* __restrict__ A,
                                                  const bf16_t* __restrict__ Bt,
                                                  void* __restrict__ Cout,
                                                  int M, int N, int K) {
  __shared__ bf16_t As[128 * 64];   // row-major [128][64], linear (gload_lds requires)
  __shared__ bf16_t Bs[128 * 64];
  const int tid = threadIdx.x;
  const int lane = tid & 63, wave = tid >> 6;
  const int l15 = lane & 15, lhi = lane >> 4;
  const int bm = blockIdx.y * 128, bn = blockIdx.x * 128;
  const int wr = (wave >> 1) * 64, wc = (wave & 1) * 64;

  f32x4 acc[4][4] = {};

  // Staging geometry: call c covers LDS bytes [c*4096 + wave*1024, +1024) per wave.
  // Lane l's 16B lands at row = c*32 + wave*8 + (l>>3), elem col = (l&7)*8.
  const int srow = wave * 8 + (lane >> 3);
  const int scol = (lane & 7) * 8;
  const bf16_t* Ag = A + (size_t)(bm + srow) * K + scol;
  const bf16_t* Bg = Bt + (size_t)(bn + srow) * K + scol;
  char* AsB = (char*)As + wave * 1024 + 0;   // wave-uniform LDS base
  char* BsB = (char*)Bs + wave * 1024 + 0;

  for (int bk = 0; bk < K; bk += 64) {
#pragma unroll
    for (int c = 0; c < 4; c++) {
      GLOAD_LDS16(Ag + (size_t)(c * 32) * K + bk, AsB + c * 4096);
      GLOAD_LDS16(Bg + (size_t)(c * 32) * K + bk, BsB + c * 4096);
    }
    __syncthreads();   // compiler drains vmcnt before s_barrier -> LDS tiles ready
#pragma unroll
    for (int ks = 0; ks < 2; ks++) {
      bf16x8 af[4], bfr[4];
#pragma unroll
      for (int i = 0; i < 4; i++)
        af[i] = *(const bf16x8*)&As[(wr + i * 16 + l15) * 64 + ks * 32 + lhi * 8];
#pragma unroll
      for (int j = 0; j < 4; j++)
        bfr[j] = *(const bf16x8*)&Bs[(wc + j * 16 + l15) * 64 + ks * 32 + lhi * 8];
#pragma unroll
      for (int i = 0; i < 4; i++)
#pragma unroll
        for (int j = 0; j < 4; j++)
          acc[i][j] = __builtin_amdgcn_mfma_f32_16x16x32_bf16(af[i], bfr[j], acc[i][j], 0, 0, 0);
    }
    __syncthreads();   // protect LDS from next stage
  }

#pragma unroll
  for (int i = 0; i < 4; i++)
#pragma unroll
    for (int j = 0; j < 4; j++)
#pragma unroll
      for (int b = 0; b < 4; b++) {
        int row = bm + wr + i * 16 + lhi * 4 + b;
        int col = bn + wc + j * 16 + l15;
        float v = acc[i][j][b];
        if (OUT_F32)
          ((float*)Cout)[(size_t)row * N + col] = v;
        else
          ((bf16_t*)Cout)[(size_t)row * N + col] = (bf16_t)v;
      }
}

// ---------------- Flash attention (causal, GQA) ----------------
// grid (NH, T/128); 256 threads = 4 waves, wave w owns q-rows [w*32, w*32+32).
// KV tile = 64. Q pre-scaled by GSCALE in rope.
__global__ __launch_bounds__(256) void k_flash(const bf16_t* __restrict__ qkv,
                                               const bf16_t* __restrict__ vT,
                                               bf16_t* __restrict__ attn) {
  __shared__ bf16_t Kl[64][152];   // [s][d] pad 152 (304B stride)
  __shared__ bf16_t Vl[128][88];   // [d][s] pad 88
  __shared__ bf16_t Pl[128][88];   // [t][s] pad 88
  const int h = blockIdx.x;
  const int qt = blockIdx.y;
  const int kvh = h >> 2;
  const int tid = threadIdx.x, lane = tid & 63, wave = tid >> 6;
  const int l15 = lane & 15, lhi = lane >> 4;
  const int qbase = qt * 128, wrow = wave * 32;

  // Q fragments, persistent in registers
  bf16x8 qf[2][4];
#pragma unroll
  for (int i = 0; i < 2; i++)
#pragma unroll
    for (int ks = 0; ks < 4; ks++)
      qf[i][ks] = *(const bf16x8*)&qkv[(size_t)(qbase + wrow + i * 16 + l15) * QKVN +
                                       h * 128 + ks * 32 + lhi * 8];

  f32x4 o[2][8] = {};
  float m_i[2][4], l_i[2][4];
#pragma unroll
  for (int i = 0; i < 2; i++)
#pragma unroll
    for (int b = 0; b < 4; b++) { m_i[i][b] = -1e30f; l_i[i][b] = 0.f; }

  const int ktmax = (qbase + 127) >> 6;
  for (int kt = 0; kt <= ktmax; kt++) {
    // stage K (64x128) and Vt (128x64) via regs
    float4 rk[4], rv[4];
#pragma unroll
    for (int r = 0; r < 4; r++) {
      int ck = r * 256 + tid;
      int s = ck >> 4, dc = (ck & 15) * 8;
      rk[r] = *(const float4*)&qkv[(size_t)(kt * 64 + s) * QKVN + 4096 + kvh * 128 + dc];
      int d = ck >> 3, scc = (ck & 7) * 8;
      rv[r] = *(const float4*)&vT[(size_t)(kvh * 128 + d) * TSEQ + kt * 64 + scc];
    }
    __syncthreads();
#pragma unroll
    for (int r = 0; r < 4; r++) {
      int ck = r * 256 + tid;
      int s = ck >> 4, dc = (ck & 15) * 8;
      *(float4*)&Kl[s][dc] = rk[r];
      int d = ck >> 3, scc = (ck & 7) * 8;
      *(float4*)&Vl[d][scc] = rv[r];
    }
    __syncthreads();

    // S = Q * K^T  (per wave: 32 x 64)
    f32x4 sa[2][4] = {};
#pragma unroll
    for (int ks = 0; ks < 4; ks++) {
      bf16x8 kb[4];
#pragma unroll
      for (int j = 0; j < 4; j++)
        kb[j] = *(const bf16x8*)&Kl[j * 16 + l15][ks * 32 + lhi * 8];
#pragma unroll
      for (int i = 0; i < 2; i++)
#pragma unroll
        for (int j = 0; j < 4; j++)
          sa[i][j] = __builtin_amdgcn_mfma_f32_16x16x32_bf16(qf[i][ks], kb[j], sa[i][j], 0, 0, 0);
    }

    // mask + online softmax
#pragma unroll
    for (int i = 0; i < 2; i++) {
#pragma unroll
      for (int b = 0; b < 4; b++) {
        int trow = qbase + wrow + i * 16 + lhi * 4 + b;
        float mx = -1e30f;
#pragma unroll
        for (int j = 0; j < 4; j++) {
          int scol = kt * 64 + j * 16 + l15;
          if (scol > trow) sa[i][j][b] = -1e30f;
          mx = fmaxf(mx, sa[i][j][b]);
        }
#pragma unroll
        for (int off = 1; off < 16; off <<= 1) mx = fmaxf(mx, __shfl_xor(mx, off));
        float mn = fmaxf(m_i[i][b], mx);
        float corr = __expf(m_i[i][b] - mn);
        float sum = 0.f;
#pragma unroll
        for (int j = 0; j < 4; j++) {
          float pv = __expf(sa[i][j][b] - mn);
          sa[i][j][b] = pv;
          sum += pv;
        }
#pragma unroll
        for (int off = 1; off < 16; off <<= 1) sum += __shfl_xor(sum, off);
        l_i[i][b] = l_i[i][b] * corr + sum;
        m_i[i][b] = mn;
#pragma unroll
        for (int j = 0; j < 8; j++) o[i][j][b] *= corr;
#pragma unroll
        for (int j = 0; j < 4; j++)
          Pl[wrow + i * 16 + lhi * 4 + b][j * 16 + l15] = (bf16_t)sa[i][j][b];
      }
    }

    // O += P * V   (P: 32x64 A-frags via LDS; V: B-frags from Vl)
#pragma unroll
    for (int ks = 0; ks < 2; ks++) {
      bf16x8 pa[2], vb[8];
#pragma unroll
      for (int i = 0; i < 2; i++)
        pa[i] = *(const bf16x8*)&Pl[wrow + i * 16 + l15][ks * 32 + lhi * 8];
#pragma unroll
      for (int j = 0; j < 8; j++)
        vb[j] = *(const bf16x8*)&Vl[j * 16 + l15][ks * 32 + lhi * 8];
#pragma unroll
      for (int i = 0; i < 2; i++)
#pragma unroll
        for (int j = 0; j < 8; j++)
          o[i][j] = __builtin_amdgcn_mfma_f32_16x16x32_bf16(pa[i], vb[j], o[i][j], 0, 0, 0);
    }
    __syncthreads();
  }

  // write attn output (bf16), divided by l
#pragma unroll
  for (int i = 0; i < 2; i++)
#pragma unroll
    for (int j = 0; j < 8; j++)
#pragma unroll
      for (int b = 0; b < 4; b++) {
        int trow = qbase + wrow + i * 16 + lhi * 4 + b;
        attn[(size_t)trow * (NH * HD) + h * 128 + j * 16 + l15] =
            (bf16_t)(o[i][j][b] / l_i[i][b]);
      }
}

// ---------------- launcher ----------------
extern "C" void kernel_launch(void* const* d_in, const int* in_sizes, int n_in,
                              void* d_out, int out_size, void* d_ws, size_t ws_size,
                              hipStream_t stream) {
  const int* positions = (const int*)d_in[0];
  const float* hs = (const float*)d_in[1];
  const float* wqkv = (const float*)d_in[2];
  const float* wo = (const float*)d_in[3];
  float* out = (float*)d_out;

  char* ws = (char*)d_ws;
  bf16_t* hsb   = (bf16_t*)(ws);                       // 16.78 MB  (reused as attn later)
  bf16_t* wqkvT = (bf16_t*)(ws + 16777216);            // 50.33 MB
  bf16_t* woT   = (bf16_t*)(ws + 67108864);            // 33.55 MB
  bf16_t* qkv   = (bf16_t*)(ws + 100663296);           // 25.17 MB
  bf16_t* vT    = (bf16_t*)(ws + 125829120);           //  4.19 MB
  bf16_t* attn  = hsb;                                 // reuse (hsb dead after GEMM1)

  // 1. convert hidden_states
  k_f32_to_bf16<<<(TSEQ * HID / 4 + 255) / 256, 256, 0, stream>>>(hs, hsb, TSEQ * HID);
  // 2. transpose-convert weights to [N][K]
  k_transpose_f32_bf16<<<dim3(QKVN / 32, HID / 32), 256, 0, stream>>>(wqkv, wqkvT, HID, QKVN);
  k_transpose_f32_bf16<<<dim3(HID / 32, HID / 32), 256, 0, stream>>>(wo, woT, NH * HD, HID);
  // 3. QKV projection -> qkv bf16 [T][6144]
  k_gemm_lds<0><<<dim3(QKVN / 128, TSEQ / 128), 256, 0, stream>>>(hsb, wqkvT, qkv, TSEQ, QKVN, HID);
  // 4. RoPE in place (q scaled)
  k_rope<<<dim3(10, TSEQ), 256, 0, stream>>>(qkv, positions);
  // 5. transpose V -> vT [1024][T]
  k_transpose_v<<<dim3(TSEQ / 32, 1024 / 32), 256, 0, stream>>>(qkv, vT);
  // 6. flash attention -> attn bf16 [T][4096]
  k_flash<<<dim3(NH, TSEQ / 128), 256, 0, stream>>>(qkv, vT, attn);
  // 7. output projection -> f32 out
  k_gemm_lds<1><<<dim3(HID / 128, TSEQ / 128), 256, 0, stream>>>(attn, woT, out, TSEQ, HID, HID);
}

// Round 4
// 494.704 us; speedup vs baseline: 2.1244x; 1.1121x over previous
//
#include <hip/hip_runtime.h>
#include <hip/hip_bf16.h>
#include <math.h>

// Problem constants
#define TSEQ   2048
#define HID    4096
#define NH     32
#define NKV    8
#define HD     128
#define QKVN   6144              // NH*HD + 2*NKV*HD
#define GSCALE 0.08838834764831845f   // HD^-0.5
#define LOG_THETA 13.122363377404328f // ln(500000)

typedef __bf16 bf16_t;
typedef __attribute__((ext_vector_type(8))) __bf16 bf16x8;
typedef __attribute__((ext_vector_type(4))) float f32x4;

// async global->LDS, 16B per lane; LDS dest is wave-uniform base + lane*16
#define GLOAD_LDS16(gp, lp)                                                    \
  __builtin_amdgcn_global_load_lds(                                            \
      (const __attribute__((address_space(1))) void*)(gp),                     \
      (__attribute__((address_space(3))) void*)(lp), 16, 0, 0)

// ---------------- f32 -> bf16 elementwise convert ----------------
__global__ __launch_bounds__(256) void k_f32_to_bf16(const float* __restrict__ in,
                                                     bf16_t* __restrict__ out, int n) {
  int i = (blockIdx.x * 256 + threadIdx.x) * 4;
  if (i >= n) return;
  float4 v = *(const float4*)(in + i);
  bf16_t o0 = (bf16_t)v.x, o1 = (bf16_t)v.y, o2 = (bf16_t)v.z, o3 = (bf16_t)v.w;
  typedef __attribute__((ext_vector_type(4))) __bf16 bf16x4;
  bf16x4 o = {o0, o1, o2, o3};
  *(bf16x4*)(out + i) = o;
}

// ---------------- f32 [R][C] -> bf16 [C][R] transpose-convert ----------------
__global__ __launch_bounds__(256) void k_transpose_f32_bf16(const float* __restrict__ in,
                                                            bf16_t* __restrict__ out,
                                                            int R, int C) {
  __shared__ float tile[32][33];
  int tx = threadIdx.x & 31, ty = threadIdx.x >> 5;
  int c0 = blockIdx.x * 32, r0 = blockIdx.y * 32;
#pragma unroll
  for (int i = 0; i < 4; i++)
    tile[ty + i * 8][tx] = in[(size_t)(r0 + ty + i * 8) * C + c0 + tx];
  __syncthreads();
#pragma unroll
  for (int i = 0; i < 4; i++)
    out[(size_t)(c0 + ty + i * 8) * R + r0 + tx] = (bf16_t)tile[tx][ty + i * 8];
}

// ---------------- RoPE (interleaved) in-place on qkv; folds GSCALE into q ----------------
__global__ __launch_bounds__(256) void k_rope(bf16_t* __restrict__ qkv,
                                              const int* __restrict__ positions) {
  int idx = blockIdx.x * 256 + threadIdx.x;   // 0..2559 = 40 heads * 64 pairs
  int t = blockIdx.y;
  int i = idx & 63;          // pair index 0..63
  int hh = idx >> 6;         // 0..39 (0..31 = q heads, 32..39 = k heads)
  if (hh >= 40) return;
  int col = (hh < 32) ? (hh * 128 + 2 * i) : (4096 + (hh - 32) * 128 + 2 * i);
  size_t base = (size_t)t * QKVN + col;
  float x1 = (float)qkv[base];
  float x2 = (float)qkv[base + 1];
  float p = (float)positions[t];
  float inv = expf(-(float)i * (LOG_THETA / 64.0f));
  float ang = p * inv;
  float s, c;
  sincosf(ang, &s, &c);
  float o1 = x1 * c - x2 * s;
  float o2 = x2 * c + x1 * s;
  float sc = (hh < 32) ? GSCALE : 1.0f;
  qkv[base]     = (bf16_t)(o1 * sc);
  qkv[base + 1] = (bf16_t)(o2 * sc);
}

// ---------------- transpose V: qkv[:, 5120+c] (T x 1024) -> vT [1024][T] ----------------
__global__ __launch_bounds__(256) void k_transpose_v(const bf16_t* __restrict__ qkv,
                                                     bf16_t* __restrict__ vT) {
  __shared__ bf16_t tile[32][33];
  int tx = threadIdx.x & 31, ty = threadIdx.x >> 5;
  int t0 = blockIdx.x * 32;   // seq tile
  int c0 = blockIdx.y * 32;   // channel tile (kv*128+d)
#pragma unroll
  for (int i = 0; i < 4; i++)
    tile[ty + i * 8][tx] = qkv[(size_t)(t0 + ty + i * 8) * QKVN + 5120 + c0 + tx];
  __syncthreads();
#pragma unroll
  for (int i = 0; i < 4; i++)
    vT[(size_t)(c0 + ty + i * 8) * TSEQ + t0 + tx] = tile[tx][ty + i * 8];
}

// ================= 256x256 8-phase GEMM (T2+T3+T4+T5) =================
// C[M][N] = A[M][K] * Bt[N][K]^T, bf16 in, f32 acc.
// 512 threads = 8 waves (2M x 4N), per-wave out 128x64 (8x4 16x16 frags).
// LDS: 2 x [256][64] per matrix, double-buffered = 128 KB.
// Swizzle (T2): LDS[r][c16-chunk] holds G[r][c16 ^ (r&7)] (involution, 16B granule);
// gload dest linear, source pre-swizzled; ds_read applies same XOR.
// K-tile staged as 8 gload chunks (64 rows each), order b0,b1,b2,b3,a0,a2,a1,a3.
// Phases read: P1 = A rows [wr*128,+64) + B cols [wc*64,+32)  -> needs b*,a0,a2
//              P2 = B cols [wc*64+32,+32)                      -> same b chunk
//              P3 = A rows [wr*128+64,+64)                     -> needs a1,a3
//              P4 = regs only.
// vmcnt ladder (per-thread, 2 issues/phase for next tile):
//   P4-end vmcnt(2): all but {a1,a3}-of-next landed -> next P1/P2 safe.
//   P2-end vmcnt(4): {a1,a3}-of-current landed      -> P3 safe.  Never 0 in loop.
template <int OUT_F32>
__global__ __launch_bounds__(512, 2) void k_gemm256(const bf16_t* __restrict__ A,
                                                    const bf16_t* __restrict__ Bt,
                                                    void* __restrict__ Cout,
                                                    int M, int N, int K) {
  __shared__ bf16_t sA[2 * 256 * 64];   // 64 KB
  __shared__ bf16_t sB[2 * 256 * 64];   // 64 KB
  const int tid = threadIdx.x;
  const int lane = tid & 63, wave = tid >> 6;
  const int l15 = lane & 15, lhi = lane >> 4, l7 = l15 & 7;
  const int wr = wave >> 2, wc = wave & 3;
  const int wr128 = wr * 128, wc64 = wc * 64;
  const int bm = blockIdx.y * 256, bn = blockIdx.x * 256;
  const int nkt = K >> 6;

  // staging geometry: chunk = 64 rows x 64 cols (8 KB), 1 gload instr / chunk.
  // thread -> (row r8 = tid>>3, c16 = (tid&7) ^ (r8&7))  [source pre-swizzle]
  const int r8 = tid >> 3;
  const int c16 = (tid & 7) ^ (r8 & 7);
  const bf16_t* Ag = A + (size_t)(bm + r8) * K + c16 * 8;
  const bf16_t* Bg = Bt + (size_t)(bn + r8) * K + c16 * 8;
  char* sAb = (char*)sA + wave * 1024;   // wave-uniform LDS bases
  char* sBb = (char*)sB + wave * 1024;

// A-chunk issue order {0,2,1,3} = 2-bit reversal of (q-4); plain arithmetic so
// the dead branch still type-checks for q<4 (round-3 compile fix).
#define STAGE(dst, bkk, q)                                                        \
  do {                                                                            \
    if ((q) < 4) {                                                                \
      GLOAD_LDS16(Bg + (size_t)((q) * 64) * K + (bkk),                            \
                  sBb + (dst) * 32768 + (q) * 8192);                              \
    } else {                                                                      \
      const int ar2_ = ((((q) - 4) & 1) << 1) | ((((q) - 4) >> 1) & 1);           \
      GLOAD_LDS16(Ag + (size_t)(ar2_ * 64) * K + (bkk),                           \
                  sAb + (dst) * 32768 + ar2_ * 8192);                             \
    }                                                                             \
  } while (0)

// swizzled fragment reads (element index; row&7 == l15&7 for 16-aligned rows)
#define RD_A(m, ks) (*(const bf16x8*)&sA[dofs + ((wr128 + (m) * 16 + l15) << 6) + \
                                         ((((ks) * 4 + lhi) ^ l7) << 3)])
#define RD_B(n, ks) (*(const bf16x8*)&sB[dofs + ((wc64 + (n) * 16 + l15) << 6) +  \
                                         ((((ks) * 4 + lhi) ^ l7) << 3)])

  f32x4 acc[8][4] = {};
  bf16x8 ar_[4][2], b01[2][2], b23[2][2];

  // prologue: stage tile 0 -> buf 0 (issue order b0,b1,b2,b3,a0,a2,a1,a3)
  STAGE(0, 0, 0); STAGE(0, 0, 1); STAGE(0, 0, 2); STAGE(0, 0, 3);
  STAGE(0, 0, 4); STAGE(0, 0, 5); STAGE(0, 0, 6); STAGE(0, 0, 7);
  asm volatile("s_waitcnt vmcnt(2)" ::: "memory");
  __builtin_amdgcn_s_barrier();

  for (int t = 0; t < nkt; ++t) {
    const int d = t & 1, dn = d ^ 1;
    const int dofs = d * 16384;          // element offset of current buffer
    const int bk1 = (t + 1) << 6;
    const bool pf = (t + 1 < nkt);

    // ---------- Phase 1: read A m0-3 + B n0-1; stage b0,b1 ----------
#pragma unroll
    for (int m = 0; m < 4; m++)
#pragma unroll
      for (int ks = 0; ks < 2; ks++) ar_[m][ks] = RD_A(m, ks);
#pragma unroll
    for (int n = 0; n < 2; n++)
#pragma unroll
      for (int ks = 0; ks < 2; ks++) b01[n][ks] = RD_B(n, ks);
    if (pf) { STAGE(dn, bk1, 0); STAGE(dn, bk1, 1); }
    __builtin_amdgcn_s_barrier();
    asm volatile("s_waitcnt lgkmcnt(0)" ::: "memory");
    __builtin_amdgcn_sched_barrier(0);
    __builtin_amdgcn_s_setprio(1);
#pragma unroll
    for (int m = 0; m < 4; m++)
#pragma unroll
      for (int n = 0; n < 2; n++)
#pragma unroll
        for (int ks = 0; ks < 2; ks++)
          acc[m][n] = __builtin_amdgcn_mfma_f32_16x16x32_bf16(ar_[m][ks], b01[n][ks], acc[m][n], 0, 0, 0);
    __builtin_amdgcn_s_setprio(0);
    __builtin_amdgcn_s_barrier();

    // ---------- Phase 2: read B n2-3; stage b2,b3; vmcnt(4) ----------
#pragma unroll
    for (int n = 0; n < 2; n++)
#pragma unroll
      for (int ks = 0; ks < 2; ks++) b23[n][ks] = RD_B(2 + n, ks);
    if (pf) { STAGE(dn, bk1, 2); STAGE(dn, bk1, 3); }
    __builtin_amdgcn_s_barrier();
    asm volatile("s_waitcnt lgkmcnt(0)" ::: "memory");
    __builtin_amdgcn_sched_barrier(0);
    __builtin_amdgcn_s_setprio(1);
#pragma unroll
    for (int m = 0; m < 4; m++)
#pragma unroll
      for (int n = 0; n < 2; n++)
#pragma unroll
        for (int ks = 0; ks < 2; ks++)
          acc[m][2 + n] = __builtin_amdgcn_mfma_f32_16x16x32_bf16(ar_[m][ks], b23[n][ks], acc[m][2 + n], 0, 0, 0);
    __builtin_amdgcn_s_setprio(0);
    asm volatile("s_waitcnt vmcnt(4)" ::: "memory");   // a1,a3 of current tile landed
    __builtin_amdgcn_s_barrier();

    // ---------- Phase 3: read A m4-7; stage a0,a2 ----------
#pragma unroll
    for (int m = 0; m < 4; m++)
#pragma unroll
      for (int ks = 0; ks < 2; ks++) ar_[m][ks] = RD_A(4 + m, ks);
    if (pf) { STAGE(dn, bk1, 4); STAGE(dn, bk1, 5); }
    __builtin_amdgcn_s_barrier();
    asm volatile("s_waitcnt lgkmcnt(0)" ::: "memory");
    __builtin_amdgcn_sched_barrier(0);
    __builtin_amdgcn_s_setprio(1);
#pragma unroll
    for (int m = 0; m < 4; m++)
#pragma unroll
      for (int n = 0; n < 2; n++)
#pragma unroll
        for (int ks = 0; ks < 2; ks++)
          acc[4 + m][2 + n] = __builtin_amdgcn_mfma_f32_16x16x32_bf16(ar_[m][ks], b23[n][ks], acc[4 + m][2 + n], 0, 0, 0);
    __builtin_amdgcn_s_setprio(0);
    __builtin_amdgcn_s_barrier();

    // ---------- Phase 4: regs only; stage a1,a3; vmcnt(2) ----------
    if (pf) { STAGE(dn, bk1, 6); STAGE(dn, bk1, 7); }
    __builtin_amdgcn_s_barrier();
    __builtin_amdgcn_s_setprio(1);
#pragma unroll
    for (int m = 0; m < 4; m++)
#pragma unroll
      for (int n = 0; n < 2; n++)
#pragma unroll
        for (int ks = 0; ks < 2; ks++)
          acc[4 + m][n] = __builtin_amdgcn_mfma_f32_16x16x32_bf16(ar_[m][ks], b01[n][ks], acc[4 + m][n], 0, 0, 0);
    __builtin_amdgcn_s_setprio(0);
    asm volatile("s_waitcnt vmcnt(2)" ::: "memory");   // next tile's b*,a0,a2 landed
    __builtin_amdgcn_s_barrier();
  }
#undef STAGE
#undef RD_A
#undef RD_B

  // epilogue: C write (C/D layout: col=lane&15, row=(lane>>4)*4+reg)
#pragma unroll
  for (int m = 0; m < 8; m++)
#pragma unroll
    for (int n = 0; n < 4; n++)
#pragma unroll
      for (int b = 0; b < 4; b++) {
        int row = bm + wr128 + m * 16 + lhi * 4 + b;
        int col = bn + wc64 + n * 16 + l15;
        float v = acc[m][n][b];
        if (OUT_F32)
          ((float*)Cout)[(size_t)row * N + col] = v;
        else
          ((bf16_t*)Cout)[(size_t)row * N + col] = (bf16_t)v;
      }
}

// ---------------- Flash attention (causal, GQA) ----------------
// grid (NH, T/128); 256 threads = 4 waves, wave w owns q-rows [w*32, w*32+32).
// KV tile = 64. Q pre-scaled by GSCALE in rope.
__global__ __launch_bounds__(256) void k_flash(const bf16_t* __restrict__ qkv,
                                               const bf16_t* __restrict__ vT,
                                               bf16_t* __restrict__ attn) {
  __shared__ bf16_t Kl[64][152];   // [s][d] pad 152 (304B stride)
  __shared__ bf16_t Vl[128][88];   // [d][s] pad 88
  __shared__ bf16_t Pl[128][88];   // [t][s] pad 88
  const int h = blockIdx.x;
  const int qt = blockIdx.y;
  const int kvh = h >> 2;
  const int tid = threadIdx.x, lane = tid & 63, wave = tid >> 6;
  const int l15 = lane & 15, lhi = lane >> 4;
  const int qbase = qt * 128, wrow = wave * 32;

  // Q fragments, persistent in registers
  bf16x8 qf[2][4];
#pragma unroll
  for (int i = 0; i < 2; i++)
#pragma unroll
    for (int ks = 0; ks < 4; ks++)
      qf[i][ks] = *(const bf16x8*)&qkv[(size_t)(qbase + wrow + i * 16 + l15) * QKVN +
                                       h * 128 + ks * 32 + lhi * 8];

  f32x4 o[2][8] = {};
  float m_i[2][4], l_i[2][4];
#pragma unroll
  for (int i = 0; i < 2; i++)
#pragma unroll
    for (int b = 0; b < 4; b++) { m_i[i][b] = -1e30f; l_i[i][b] = 0.f; }

  const int ktmax = (qbase + 127) >> 6;
  for (int kt = 0; kt <= ktmax; kt++) {
    // stage K (64x128) and Vt (128x64) via regs
    float4 rk[4], rv[4];
#pragma unroll
    for (int r = 0; r < 4; r++) {
      int ck = r * 256 + tid;
      int s = ck >> 4, dc = (ck & 15) * 8;
      rk[r] = *(const float4*)&qkv[(size_t)(kt * 64 + s) * QKVN + 4096 + kvh * 128 + dc];
      int d = ck >> 3, scc = (ck & 7) * 8;
      rv[r] = *(const float4*)&vT[(size_t)(kvh * 128 + d) * TSEQ + kt * 64 + scc];
    }
    __syncthreads();
#pragma unroll
    for (int r = 0; r < 4; r++) {
      int ck = r * 256 + tid;
      int s = ck >> 4, dc = (ck & 15) * 8;
      *(float4*)&Kl[s][dc] = rk[r];
      int d = ck >> 3, scc = (ck & 7) * 8;
      *(float4*)&Vl[d][scc] = rv[r];
    }
    __syncthreads();

    // S = Q * K^T  (per wave: 32 x 64)
    f32x4 sa[2][4] = {};
#pragma unroll
    for (int ks = 0; ks < 4; ks++) {
      bf16x8 kb[4];
#pragma unroll
      for (int j = 0; j < 4; j++)
        kb[j] = *(const bf16x8*)&Kl[j * 16 + l15][ks * 32 + lhi * 8];
#pragma unroll
      for (int i = 0; i < 2; i++)
#pragma unroll
        for (int j = 0; j < 4; j++)
          sa[i][j] = __builtin_amdgcn_mfma_f32_16x16x32_bf16(qf[i][ks], kb[j], sa[i][j], 0, 0, 0);
    }

    // mask + online softmax
#pragma unroll
    for (int i = 0; i < 2; i++) {
#pragma unroll
      for (int b = 0; b < 4; b++) {
        int trow = qbase + wrow + i * 16 + lhi * 4 + b;
        float mx = -1e30f;
#pragma unroll
        for (int j = 0; j < 4; j++) {
          int scol = kt * 64 + j * 16 + l15;
          if (scol > trow) sa[i][j][b] = -1e30f;
          mx = fmaxf(mx, sa[i][j][b]);
        }
#pragma unroll
        for (int off = 1; off < 16; off <<= 1) mx = fmaxf(mx, __shfl_xor(mx, off));
        float mn = fmaxf(m_i[i][b], mx);
        float corr = __expf(m_i[i][b] - mn);
        float sum = 0.f;
#pragma unroll
        for (int j = 0; j < 4; j++) {
          float pv = __expf(sa[i][j][b] - mn);
          sa[i][j][b] = pv;
          sum += pv;
        }
#pragma unroll
        for (int off = 1; off < 16; off <<= 1) sum += __shfl_xor(sum, off);
        l_i[i][b] = l_i[i][b] * corr + sum;
        m_i[i][b] = mn;
#pragma unroll
        for (int j = 0; j < 8; j++) o[i][j][b] *= corr;
#pragma unroll
        for (int j = 0; j < 4; j++)
          Pl[wrow + i * 16 + lhi * 4 + b][j * 16 + l15] = (bf16_t)sa[i][j][b];
      }
    }

    // O += P * V   (P: 32x64 A-frags via LDS; V: B-frags from Vl)
#pragma unroll
    for (int ks = 0; ks < 2; ks++) {
      bf16x8 pa[2], vb[8];
#pragma unroll
      for (int i = 0; i < 2; i++)
        pa[i] = *(const bf16x8*)&Pl[wrow + i * 16 + l15][ks * 32 + lhi * 8];
#pragma unroll
      for (int j = 0; j < 8; j++)
        vb[j] = *(const bf16x8*)&Vl[j * 16 + l15][ks * 32 + lhi * 8];
#pragma unroll
      for (int i = 0; i < 2; i++)
#pragma unroll
        for (int j = 0; j < 8; j++)
          o[i][j] = __builtin_amdgcn_mfma_f32_16x16x32_bf16(pa[i], vb[j], o[i][j], 0, 0, 0);
    }
    __syncthreads();
  }

  // write attn output (bf16), divided by l
#pragma unroll
  for (int i = 0; i < 2; i++)
#pragma unroll
    for (int j = 0; j < 8; j++)
#pragma unroll
      for (int b = 0; b < 4; b++) {
        int trow = qbase + wrow + i * 16 + lhi * 4 + b;
        attn[(size_t)trow * (NH * HD) + h * 128 + j * 16 + l15] =
            (bf16_t)(o[i][j][b] / l_i[i][b]);
      }
}

// ---------------- launcher ----------------
extern "C" void kernel_launch(void* const* d_in, const int* in_sizes, int n_in,
                              void* d_out, int out_size, void* d_ws, size_t ws_size,
                              hipStream_t stream) {
  const int* positions = (const int*)d_in[0];
  const float* hs = (const float*)d_in[1];
  const float* wqkv = (const float*)d_in[2];
  const float* wo = (const float*)d_in[3];
  float* out = (float*)d_out;

  char* ws = (char*)d_ws;
  bf16_t* hsb   = (bf16_t*)(ws);                       // 16.78 MB  (reused as attn later)
  bf16_t* wqkvT = (bf16_t*)(ws + 16777216);            // 50.33 MB
  bf16_t* woT   = (bf16_t*)(ws + 67108864);            // 33.55 MB
  bf16_t* qkv   = (bf16_t*)(ws + 100663296);           // 25.17 MB
  bf16_t* vT    = (bf16_t*)(ws + 125829120);           //  4.19 MB
  bf16_t* attn  = hsb;                                 // reuse (hsb dead after GEMM1)

  // 1. convert hidden_states
  k_f32_to_bf16<<<(TSEQ * HID / 4 + 255) / 256, 256, 0, stream>>>(hs, hsb, TSEQ * HID);
  // 2. transpose-convert weights to [N][K]
  k_transpose_f32_bf16<<<dim3(QKVN / 32, HID / 32), 256, 0, stream>>>(wqkv, wqkvT, HID, QKVN);
  k_transpose_f32_bf16<<<dim3(HID / 32, HID / 32), 256, 0, stream>>>(wo, woT, NH * HD, HID);
  // 3. QKV projection -> qkv bf16 [T][6144]  (256^2 8-phase)
  k_gemm256<0><<<dim3(QKVN / 256, TSEQ / 256), 512, 0, stream>>>(hsb, wqkvT, qkv, TSEQ, QKVN, HID);
  // 4. RoPE in place (q scaled)
  k_rope<<<dim3(10, TSEQ), 256, 0, stream>>>(qkv, positions);
  // 5. transpose V -> vT [1024][T]
  k_transpose_v<<<dim3(TSEQ / 32, 1024 / 32), 256, 0, stream>>>(qkv, vT);
  // 6. flash attention -> attn bf16 [T][4096]
  k_flash<<<dim3(NH, TSEQ / 128), 256, 0, stream>>>(qkv, vT, attn);
  // 7. output projection -> f32 out  (256^2 8-phase)
  k_gemm256<1><<<dim3(HID / 256, TSEQ / 256), 512, 0, stream>>>(attn, woT, out, TSEQ, HID, HID);
}

// Round 5
// 447.981 us; speedup vs baseline: 2.3459x; 1.1043x over previous
//
#include <hip/hip_runtime.h>
#include <hip/hip_bf16.h>
#include <math.h>

// Problem constants
#define TSEQ   2048
#define HID    4096
#define NH     32
#define NKV    8
#define HD     128
#define QKVN   6144              // NH*HD + 2*NKV*HD
#define GSCALE 0.08838834764831845f   // HD^-0.5
#define LOG_THETA 13.122363377404328f // ln(500000)

typedef __bf16 bf16_t;
typedef __attribute__((ext_vector_type(8))) __bf16 bf16x8;
typedef __attribute__((ext_vector_type(4))) float f32x4;

// async global->LDS, 16B per lane; LDS dest is wave-uniform base + lane*16
#define GLOAD_LDS16(gp, lp)                                                    \
  __builtin_amdgcn_global_load_lds(                                            \
      (const __attribute__((address_space(1))) void*)(gp),                     \
      (__attribute__((address_space(3))) void*)(lp), 16, 0, 0)

// ---------------- f32 -> bf16 elementwise convert ----------------
__global__ __launch_bounds__(256) void k_f32_to_bf16(const float* __restrict__ in,
                                                     bf16_t* __restrict__ out, int n) {
  int i = (blockIdx.x * 256 + threadIdx.x) * 4;
  if (i >= n) return;
  float4 v = *(const float4*)(in + i);
  bf16_t o0 = (bf16_t)v.x, o1 = (bf16_t)v.y, o2 = (bf16_t)v.z, o3 = (bf16_t)v.w;
  typedef __attribute__((ext_vector_type(4))) __bf16 bf16x4;
  bf16x4 o = {o0, o1, o2, o3};
  *(bf16x4*)(out + i) = o;
}

// ---------------- f32 [R][C] -> bf16 [C][R] transpose-convert ----------------
__global__ __launch_bounds__(256) void k_transpose_f32_bf16(const float* __restrict__ in,
                                                            bf16_t* __restrict__ out,
                                                            int R, int C) {
  __shared__ float tile[32][33];
  int tx = threadIdx.x & 31, ty = threadIdx.x >> 5;
  int c0 = blockIdx.x * 32, r0 = blockIdx.y * 32;
#pragma unroll
  for (int i = 0; i < 4; i++)
    tile[ty + i * 8][tx] = in[(size_t)(r0 + ty + i * 8) * C + c0 + tx];
  __syncthreads();
#pragma unroll
  for (int i = 0; i < 4; i++)
    out[(size_t)(c0 + ty + i * 8) * R + r0 + tx] = (bf16_t)tile[tx][ty + i * 8];
}

// ---------------- RoPE (interleaved) in-place on qkv; folds GSCALE into q ----------------
__global__ __launch_bounds__(256) void k_rope(bf16_t* __restrict__ qkv,
                                              const int* __restrict__ positions) {
  int idx = blockIdx.x * 256 + threadIdx.x;   // 0..2559 = 40 heads * 64 pairs
  int t = blockIdx.y;
  int i = idx & 63;          // pair index 0..63
  int hh = idx >> 6;         // 0..39 (0..31 = q heads, 32..39 = k heads)
  if (hh >= 40) return;
  int col = (hh < 32) ? (hh * 128 + 2 * i) : (4096 + (hh - 32) * 128 + 2 * i);
  size_t base = (size_t)t * QKVN + col;
  float x1 = (float)qkv[base];
  float x2 = (float)qkv[base + 1];
  float p = (float)positions[t];
  float inv = expf(-(float)i * (LOG_THETA / 64.0f));
  float ang = p * inv;
  float s, c;
  sincosf(ang, &s, &c);
  float o1 = x1 * c - x2 * s;
  float o2 = x2 * c + x1 * s;
  float sc = (hh < 32) ? GSCALE : 1.0f;
  qkv[base]     = (bf16_t)(o1 * sc);
  qkv[base + 1] = (bf16_t)(o2 * sc);
}

// ---------------- transpose V: qkv[:, 5120+c] (T x 1024) -> vT [1024][T] ----------------
__global__ __launch_bounds__(256) void k_transpose_v(const bf16_t* __restrict__ qkv,
                                                     bf16_t* __restrict__ vT) {
  __shared__ bf16_t tile[32][33];
  int tx = threadIdx.x & 31, ty = threadIdx.x >> 5;
  int t0 = blockIdx.x * 32;   // seq tile
  int c0 = blockIdx.y * 32;   // channel tile (kv*128+d)
#pragma unroll
  for (int i = 0; i < 4; i++)
    tile[ty + i * 8][tx] = qkv[(size_t)(t0 + ty + i * 8) * QKVN + 5120 + c0 + tx];
  __syncthreads();
#pragma unroll
  for (int i = 0; i < 4; i++)
    vT[(size_t)(c0 + ty + i * 8) * TSEQ + t0 + tx] = tile[tx][ty + i * 8];
}

// ================= 256x256 8-phase GEMM (T2+T3+T4+T5) =================
// C[M][N] = A[M][K] * Bt[N][K]^T, bf16 in, f32 acc.
// 512 threads = 8 waves (2M x 4N), per-wave out 128x64 (8x4 16x16 frags).
// LDS: 2 x [256][64] per matrix, double-buffered = 128 KB.
// Swizzle (T2): LDS[r][c16-chunk] holds G[r][c16 ^ (r&7)] (involution, 16B granule);
// gload dest linear, source pre-swizzled; ds_read applies same XOR.
// K-tile staged as 8 gload chunks (64 rows each), order b0,b1,b2,b3,a0,a2,a1,a3.
// vmcnt ladder: P4-end vmcnt(2), P2-end vmcnt(4). Never 0 in loop.
template <int OUT_F32>
__global__ __launch_bounds__(512, 2) void k_gemm256(const bf16_t* __restrict__ A,
                                                    const bf16_t* __restrict__ Bt,
                                                    void* __restrict__ Cout,
                                                    int M, int N, int K) {
  __shared__ bf16_t sA[2 * 256 * 64];   // 64 KB
  __shared__ bf16_t sB[2 * 256 * 64];   // 64 KB
  const int tid = threadIdx.x;
  const int lane = tid & 63, wave = tid >> 6;
  const int l15 = lane & 15, lhi = lane >> 4, l7 = l15 & 7;
  const int wr = wave >> 2, wc = wave & 3;
  const int wr128 = wr * 128, wc64 = wc * 64;
  const int bm = blockIdx.y * 256, bn = blockIdx.x * 256;
  const int nkt = K >> 6;

  // staging geometry: chunk = 64 rows x 64 cols (8 KB), 1 gload instr / chunk.
  // thread -> (row r8 = tid>>3, c16 = (tid&7) ^ (r8&7))  [source pre-swizzle]
  const int r8 = tid >> 3;
  const int c16 = (tid & 7) ^ (r8 & 7);
  const bf16_t* Ag = A + (size_t)(bm + r8) * K + c16 * 8;
  const bf16_t* Bg = Bt + (size_t)(bn + r8) * K + c16 * 8;
  char* sAb = (char*)sA + wave * 1024;   // wave-uniform LDS bases
  char* sBb = (char*)sB + wave * 1024;

// A-chunk issue order {0,2,1,3} = 2-bit reversal of (q-4); plain arithmetic so
// the dead branch still type-checks for q<4.
#define STAGE(dst, bkk, q)                                                        \
  do {                                                                            \
    if ((q) < 4) {                                                                \
      GLOAD_LDS16(Bg + (size_t)((q) * 64) * K + (bkk),                            \
                  sBb + (dst) * 32768 + (q) * 8192);                              \
    } else {                                                                      \
      const int ar2_ = ((((q) - 4) & 1) << 1) | ((((q) - 4) >> 1) & 1);           \
      GLOAD_LDS16(Ag + (size_t)(ar2_ * 64) * K + (bkk),                           \
                  sAb + (dst) * 32768 + ar2_ * 8192);                             \
    }                                                                             \
  } while (0)

// swizzled fragment reads (element index; row&7 == l15&7 for 16-aligned rows)
#define RD_A(m, ks) (*(const bf16x8*)&sA[dofs + ((wr128 + (m) * 16 + l15) << 6) + \
                                         ((((ks) * 4 + lhi) ^ l7) << 3)])
#define RD_B(n, ks) (*(const bf16x8*)&sB[dofs + ((wc64 + (n) * 16 + l15) << 6) +  \
                                         ((((ks) * 4 + lhi) ^ l7) << 3)])

  f32x4 acc[8][4] = {};
  bf16x8 ar_[4][2], b01[2][2], b23[2][2];

  // prologue: stage tile 0 -> buf 0 (issue order b0,b1,b2,b3,a0,a2,a1,a3)
  STAGE(0, 0, 0); STAGE(0, 0, 1); STAGE(0, 0, 2); STAGE(0, 0, 3);
  STAGE(0, 0, 4); STAGE(0, 0, 5); STAGE(0, 0, 6); STAGE(0, 0, 7);
  asm volatile("s_waitcnt vmcnt(2)" ::: "memory");
  __builtin_amdgcn_s_barrier();

  for (int t = 0; t < nkt; ++t) {
    const int d = t & 1, dn = d ^ 1;
    const int dofs = d * 16384;          // element offset of current buffer
    const int bk1 = (t + 1) << 6;
    const bool pf = (t + 1 < nkt);

    // ---------- Phase 1: read A m0-3 + B n0-1; stage b0,b1 ----------
#pragma unroll
    for (int m = 0; m < 4; m++)
#pragma unroll
      for (int ks = 0; ks < 2; ks++) ar_[m][ks] = RD_A(m, ks);
#pragma unroll
    for (int n = 0; n < 2; n++)
#pragma unroll
      for (int ks = 0; ks < 2; ks++) b01[n][ks] = RD_B(n, ks);
    if (pf) { STAGE(dn, bk1, 0); STAGE(dn, bk1, 1); }
    __builtin_amdgcn_s_barrier();
    asm volatile("s_waitcnt lgkmcnt(0)" ::: "memory");
    __builtin_amdgcn_sched_barrier(0);
    __builtin_amdgcn_s_setprio(1);
#pragma unroll
    for (int m = 0; m < 4; m++)
#pragma unroll
      for (int n = 0; n < 2; n++)
#pragma unroll
        for (int ks = 0; ks < 2; ks++)
          acc[m][n] = __builtin_amdgcn_mfma_f32_16x16x32_bf16(ar_[m][ks], b01[n][ks], acc[m][n], 0, 0, 0);
    __builtin_amdgcn_s_setprio(0);
    __builtin_amdgcn_s_barrier();

    // ---------- Phase 2: read B n2-3; stage b2,b3; vmcnt(4) ----------
#pragma unroll
    for (int n = 0; n < 2; n++)
#pragma unroll
      for (int ks = 0; ks < 2; ks++) b23[n][ks] = RD_B(2 + n, ks);
    if (pf) { STAGE(dn, bk1, 2); STAGE(dn, bk1, 3); }
    __builtin_amdgcn_s_barrier();
    asm volatile("s_waitcnt lgkmcnt(0)" ::: "memory");
    __builtin_amdgcn_sched_barrier(0);
    __builtin_amdgcn_s_setprio(1);
#pragma unroll
    for (int m = 0; m < 4; m++)
#pragma unroll
      for (int n = 0; n < 2; n++)
#pragma unroll
        for (int ks = 0; ks < 2; ks++)
          acc[m][2 + n] = __builtin_amdgcn_mfma_f32_16x16x32_bf16(ar_[m][ks], b23[n][ks], acc[m][2 + n], 0, 0, 0);
    __builtin_amdgcn_s_setprio(0);
    asm volatile("s_waitcnt vmcnt(4)" ::: "memory");   // a1,a3 of current tile landed
    __builtin_amdgcn_s_barrier();

    // ---------- Phase 3: read A m4-7; stage a0,a2 ----------
#pragma unroll
    for (int m = 0; m < 4; m++)
#pragma unroll
      for (int ks = 0; ks < 2; ks++) ar_[m][ks] = RD_A(4 + m, ks);
    if (pf) { STAGE(dn, bk1, 4); STAGE(dn, bk1, 5); }
    __builtin_amdgcn_s_barrier();
    asm volatile("s_waitcnt lgkmcnt(0)" ::: "memory");
    __builtin_amdgcn_sched_barrier(0);
    __builtin_amdgcn_s_setprio(1);
#pragma unroll
    for (int m = 0; m < 4; m++)
#pragma unroll
      for (int n = 0; n < 2; n++)
#pragma unroll
        for (int ks = 0; ks < 2; ks++)
          acc[4 + m][2 + n] = __builtin_amdgcn_mfma_f32_16x16x32_bf16(ar_[m][ks], b23[n][ks], acc[4 + m][2 + n], 0, 0, 0);
    __builtin_amdgcn_s_setprio(0);
    __builtin_amdgcn_s_barrier();

    // ---------- Phase 4: regs only; stage a1,a3; vmcnt(2) ----------
    if (pf) { STAGE(dn, bk1, 6); STAGE(dn, bk1, 7); }
    __builtin_amdgcn_s_barrier();
    __builtin_amdgcn_s_setprio(1);
#pragma unroll
    for (int m = 0; m < 4; m++)
#pragma unroll
      for (int n = 0; n < 2; n++)
#pragma unroll
        for (int ks = 0; ks < 2; ks++)
          acc[4 + m][n] = __builtin_amdgcn_mfma_f32_16x16x32_bf16(ar_[m][ks], b01[n][ks], acc[4 + m][n], 0, 0, 0);
    __builtin_amdgcn_s_setprio(0);
    asm volatile("s_waitcnt vmcnt(2)" ::: "memory");   // next tile's b*,a0,a2 landed
    __builtin_amdgcn_s_barrier();
  }
#undef STAGE
#undef RD_A
#undef RD_B

  // epilogue: C write (C/D layout: col=lane&15, row=(lane>>4)*4+reg)
#pragma unroll
  for (int m = 0; m < 8; m++)
#pragma unroll
    for (int n = 0; n < 4; n++)
#pragma unroll
      for (int b = 0; b < 4; b++) {
        int row = bm + wr128 + m * 16 + lhi * 4 + b;
        int col = bn + wc64 + n * 16 + l15;
        float v = acc[m][n][b];
        if (OUT_F32)
          ((float*)Cout)[(size_t)row * N + col] = v;
        else
          ((bf16_t*)Cout)[(size_t)row * N + col] = (bf16_t)v;
      }
}

// ---------------- Flash attention v2 (causal, GQA) ----------------
// grid (NH, 16); zig-zag qt remap balances causal work across CU-pairs.
// 512 threads = 8 waves; wave w owns q-rows [w*16, w*16+16) of a 128-row tile.
// KV tile = 64. T14 async-stage: loads for kt+1 issued right after LDS-write
// of kt, landing during compute. Iteration count 2qt+2 is even -> 2-step loop,
// two static register buffers, no rotation.
__global__ __launch_bounds__(512, 4) void k_flash(const bf16_t* __restrict__ qkv,
                                                  const bf16_t* __restrict__ vT,
                                                  bf16_t* __restrict__ attn) {
  __shared__ bf16_t Kl[64][152];   // [s][d] pad 152
  __shared__ bf16_t Vl[128][88];   // [d][s] pad 88
  __shared__ bf16_t Pl[128][88];   // [t][s] pad 88
  const int h = blockIdx.x;
  const int by = blockIdx.y;
  const int qt = (by < 8) ? by : 23 - by;   // zig-zag: CU pair (by, by+8) work sums const
  const int kvh = h >> 2;
  const int tid = threadIdx.x, lane = tid & 63, wave = tid >> 6;
  const int l15 = lane & 15, lhi = lane >> 4;
  const int qbase = qt * 128, wrow = wave * 16;

  // Q fragments, persistent in registers (16 rows/wave)
  bf16x8 qf[4];
#pragma unroll
  for (int ks = 0; ks < 4; ks++)
    qf[ks] = *(const bf16x8*)&qkv[(size_t)(qbase + wrow + l15) * QKVN +
                                  h * 128 + ks * 32 + lhi * 8];

  f32x4 o[8] = {};
  float m_i[4], l_i[4];
#pragma unroll
  for (int b = 0; b < 4; b++) { m_i[b] = -1e30f; l_i[b] = 0.f; }

  // staging geometry (512 threads, 2 float4/thread per matrix)
  const int ks0 = tid >> 4, kd0 = (tid & 15) * 8;          // K: rows 0..31
  const int ks1 = 32 + ks0, kd1 = kd0;                     //    rows 32..63
  const int vd0 = tid >> 3, vs0 = (tid & 7) * 8;           // V: rows 0..63
  const int vd1 = 64 + vd0, vs1 = vs0;                     //    rows 64..127
  const bf16_t* Kg = qkv + 4096 + (size_t)kvh * 128;
  const bf16_t* Vg = vT + (size_t)(kvh * 128) * TSEQ;

  auto loadkv = [&](float4* RK, float4* RV, int ktl) {
    RK[0] = *(const float4*)&Kg[(size_t)(ktl * 64 + ks0) * QKVN + kd0];
    RK[1] = *(const float4*)&Kg[(size_t)(ktl * 64 + ks1) * QKVN + kd1];
    RV[0] = *(const float4*)&Vg[(size_t)vd0 * TSEQ + ktl * 64 + vs0];
    RV[1] = *(const float4*)&Vg[(size_t)vd1 * TSEQ + ktl * 64 + vs1];
  };
  auto writekv = [&](const float4* RK, const float4* RV) {
    *(float4*)&Kl[ks0][kd0] = RK[0];
    *(float4*)&Kl[ks1][kd1] = RK[1];
    *(float4*)&Vl[vd0][vs0] = RV[0];
    *(float4*)&Vl[vd1][vs1] = RV[1];
  };

  auto compute = [&](int ktc) {
    // S = Q * K^T  (wave: 16 x 64)
    f32x4 sa[4] = {};
#pragma unroll
    for (int ks = 0; ks < 4; ks++) {
      bf16x8 kb[4];
#pragma unroll
      for (int j = 0; j < 4; j++)
        kb[j] = *(const bf16x8*)&Kl[j * 16 + l15][ks * 32 + lhi * 8];
#pragma unroll
      for (int j = 0; j < 4; j++)
        sa[j] = __builtin_amdgcn_mfma_f32_16x16x32_bf16(qf[ks], kb[j], sa[j], 0, 0, 0);
    }
    // mask + online softmax (4 rows in flight per sub-iter, one per lhi)
#pragma unroll
    for (int b = 0; b < 4; b++) {
      int trow = qbase + wrow + lhi * 4 + b;
      float mx = -1e30f;
#pragma unroll
      for (int j = 0; j < 4; j++) {
        int scol = ktc * 64 + j * 16 + l15;
        if (scol > trow) sa[j][b] = -1e30f;
        mx = fmaxf(mx, sa[j][b]);
      }
#pragma unroll
      for (int off = 1; off < 16; off <<= 1) mx = fmaxf(mx, __shfl_xor(mx, off));
      float mn = fmaxf(m_i[b], mx);
      float corr = __expf(m_i[b] - mn);
      float sum = 0.f;
#pragma unroll
      for (int j = 0; j < 4; j++) {
        float pv = __expf(sa[j][b] - mn);
        sa[j][b] = pv;
        sum += pv;
      }
#pragma unroll
      for (int off = 1; off < 16; off <<= 1) sum += __shfl_xor(sum, off);
      l_i[b] = l_i[b] * corr + sum;
      m_i[b] = mn;
#pragma unroll
      for (int j = 0; j < 8; j++) o[j][b] *= corr;
#pragma unroll
      for (int j = 0; j < 4; j++)
        Pl[wrow + lhi * 4 + b][j * 16 + l15] = (bf16_t)sa[j][b];
    }
    // O += P * V (P rows are this wave's own -> in-wave LDS ordering suffices)
#pragma unroll
    for (int ks = 0; ks < 2; ks++) {
      bf16x8 pa = *(const bf16x8*)&Pl[wrow + l15][ks * 32 + lhi * 8];
#pragma unroll
      for (int j = 0; j < 8; j++) {
        bf16x8 vb = *(const bf16x8*)&Vl[j * 16 + l15][ks * 32 + lhi * 8];
        o[j] = __builtin_amdgcn_mfma_f32_16x16x32_bf16(pa, vb, o[j], 0, 0, 0);
      }
    }
  };

  const int ktmax = qt * 2 + 1;   // always odd -> even iteration count
  float4 rkA[2], rvA[2], rkB[2], rvB[2];
  loadkv(rkA, rvA, 0);
  for (int kt = 0; kt <= ktmax; kt += 2) {
    __syncthreads();              // prev compute done, LDS writable
    writekv(rkA, rvA);
    loadkv(rkB, rvB, kt + 1);     // T14: lands during compute(kt)
    __syncthreads();              // LDS ready
    compute(kt);
    __syncthreads();
    writekv(rkB, rvB);
    if (kt + 2 <= ktmax) loadkv(rkA, rvA, kt + 2);
    __syncthreads();
    compute(kt + 1);
  }

  // write attn output (bf16), divided by l
#pragma unroll
  for (int j = 0; j < 8; j++)
#pragma unroll
    for (int b = 0; b < 4; b++) {
      int trow = qbase + wrow + lhi * 4 + b;
      attn[(size_t)trow * (NH * HD) + h * 128 + j * 16 + l15] =
          (bf16_t)(o[j][b] / l_i[b]);
    }
}

// ---------------- launcher ----------------
extern "C" void kernel_launch(void* const* d_in, const int* in_sizes, int n_in,
                              void* d_out, int out_size, void* d_ws, size_t ws_size,
                              hipStream_t stream) {
  const int* positions = (const int*)d_in[0];
  const float* hs = (const float*)d_in[1];
  const float* wqkv = (const float*)d_in[2];
  const float* wo = (const float*)d_in[3];
  float* out = (float*)d_out;

  char* ws = (char*)d_ws;
  bf16_t* hsb   = (bf16_t*)(ws);                       // 16.78 MB  (reused as attn later)
  bf16_t* wqkvT = (bf16_t*)(ws + 16777216);            // 50.33 MB
  bf16_t* woT   = (bf16_t*)(ws + 67108864);            // 33.55 MB
  bf16_t* qkv   = (bf16_t*)(ws + 100663296);           // 25.17 MB
  bf16_t* vT    = (bf16_t*)(ws + 125829120);           //  4.19 MB
  bf16_t* attn  = hsb;                                 // reuse (hsb dead after GEMM1)

  // 1. convert hidden_states
  k_f32_to_bf16<<<(TSEQ * HID / 4 + 255) / 256, 256, 0, stream>>>(hs, hsb, TSEQ * HID);
  // 2. transpose-convert weights to [N][K]
  k_transpose_f32_bf16<<<dim3(QKVN / 32, HID / 32), 256, 0, stream>>>(wqkv, wqkvT, HID, QKVN);
  k_transpose_f32_bf16<<<dim3(HID / 32, HID / 32), 256, 0, stream>>>(wo, woT, NH * HD, HID);
  // 3. QKV projection -> qkv bf16 [T][6144]  (256^2 8-phase)
  k_gemm256<0><<<dim3(QKVN / 256, TSEQ / 256), 512, 0, stream>>>(hsb, wqkvT, qkv, TSEQ, QKVN, HID);
  // 4. RoPE in place (q scaled)
  k_rope<<<dim3(10, TSEQ), 256, 0, stream>>>(qkv, positions);
  // 5. transpose V -> vT [1024][T]
  k_transpose_v<<<dim3(TSEQ / 32, 1024 / 32), 256, 0, stream>>>(qkv, vT);
  // 6. flash attention -> attn bf16 [T][4096]
  k_flash<<<dim3(NH, 16), 512, 0, stream>>>(qkv, vT, attn);
  // 7. output projection -> f32 out  (256^2 8-phase)
  k_gemm256<1><<<dim3(HID / 256, TSEQ / 256), 512, 0, stream>>>(attn, woT, out, TSEQ, HID, HID);
}